// Round 10
// baseline (245.785 us; speedup 1.0000x reference)
//
#include <hip/hip_runtime.h>
#include <math.h>

#define B_  2
#define S_  2048
#define D_  1024
#define H_  16
#define HD_ 64
#define M_  (B_*S_)

typedef __attribute__((ext_vector_type(8)))  short s8v;   // 8 bf16 (4 VGPRs)
typedef __attribute__((ext_vector_type(4)))  int   i4v;
typedef __attribute__((ext_vector_type(4)))  float f4v;
typedef __attribute__((ext_vector_type(16))) float f16x;  // 32x32 C/D
#define MFMA16(a,b,c) __builtin_amdgcn_mfma_f32_16x16x32_bf16(a,b,c,0,0,0)
#define MFMA32(a,b,c) __builtin_amdgcn_mfma_f32_32x32x16_bf16(a,b,c,0,0,0)

typedef __attribute__((address_space(1))) const unsigned int uint_ga;
typedef __attribute__((address_space(3))) unsigned int       uint_ls;

__device__ __forceinline__ unsigned short f2bf(float x) {   // RNE
    unsigned u = __float_as_uint(x);
    u += 0x7FFF + ((u >> 16) & 1);
    return (unsigned short)(u >> 16);
}
// async global->LDS, 16B per lane; LDS dest = wave-uniform base + lane*16
__device__ __forceinline__ void gld16(const unsigned short* g, short* l) {
    __builtin_amdgcn_global_load_lds((uint_ga*)g, (uint_ls*)l, 16, 0, 0);
}

#define SCALE2 0.1803368801111204f   /* 0.125 * log2(e) */
#define MXF2   16.0f

// ---------------------------------------------------------------------------
// fp32 -> bf16 for X and weights + RoPE table (fused). grid = (4096, 6)
// y==5: cos/sin table, packed float2, layout [j=0..31][s]
// ---------------------------------------------------------------------------
__global__ __launch_bounds__(256) void cvt_bf16_kernel(
    const float* __restrict__ X,  const float* __restrict__ Wq,
    const float* __restrict__ Wk, const float* __restrict__ Wv,
    const float* __restrict__ Wo,
    unsigned short* __restrict__ Xb,  unsigned short* __restrict__ Wqb,
    unsigned short* __restrict__ Wkb, unsigned short* __restrict__ Wvb,
    unsigned short* __restrict__ Wob, float2* __restrict__ cst)
{
    int y = blockIdx.y;
    if (y == 5) {
        int i = blockIdx.x * 256 + threadIdx.x;
        if (i < S_ * 32) {
            int j = i >> 11, s = i & 2047;
            double inv = pow(10000.0, -(double)j / 32.0);
            double ang = (double)s * inv;
            cst[i] = make_float2((float)cos(ang), (float)sin(ang));
        }
        return;
    }
    const float* src = (y==0)?X:(y==1)?Wq:(y==2)?Wk:(y==3)?Wv:Wo;
    unsigned short* dst = (y==0)?Xb:(y==1)?Wqb:(y==2)?Wkb:(y==3)?Wvb:Wob;
    int n = (y==0) ? (M_*D_) : (D_*D_);
    int i = (blockIdx.x*256 + threadIdx.x)*4;
    if (i >= n) return;
    float4 v = *(const float4*)&src[i];
    ushort4 o;
    o.x = f2bf(v.x); o.y = f2bf(v.y); o.z = f2bf(v.z); o.w = f2bf(v.w);
    *(ushort4*)&dst[i] = o;
}

// ---------------------------------------------------------------------------
// m97-style GEMM core: 128x128 tile of C = A . B^T (both row-major, K=D_
// contiguous). 256 thr = 4 waves; wave (wm,wn) owns a 64x64 quadrant,
// 4x4 MFMA16 accs. Staging: global_load_lds dwordx4, XOR chunk swizzle.
// ---------------------------------------------------------------------------
__device__ __forceinline__ void mfma_128x128(
    const unsigned short* __restrict__ Amat, const unsigned short* __restrict__ Bmat,
    int m0, int n0, short* As, short* Bs, f4v acc[4][4])
{
    int tid = threadIdx.x;
    int l = tid & 63, w = tid >> 6;
    int wm = w >> 1, wn = w & 1;
    int lm = l & 15, qd = l >> 4;
    int lm7 = lm & 7;

    f4v z = {0.f, 0.f, 0.f, 0.f};
#pragma unroll
    for (int mt = 0; mt < 4; mt++)
#pragma unroll
        for (int nt = 0; nt < 4; nt++) acc[mt][nt] = z;

    int rl = l >> 3;              // 0..7 row-in-group
    int kc = (l & 7) ^ rl;        // swizzled logical chunk to fetch
    const unsigned short* aG = Amat + (size_t)(m0 + w*32 + rl) * D_ + kc*8;
    const unsigned short* bG = Bmat + (size_t)(n0 + w*32 + rl) * D_ + kc*8;
    short* aL = As + (w*32)*64;
    short* bL = Bs + (w*32)*64;

#pragma unroll 1
    for (int k0 = 0; k0 < D_; k0 += 64) {
        __syncthreads();
#pragma unroll
        for (int j = 0; j < 4; j++) {
            gld16(aG + k0 + (size_t)j*8*D_, aL + j*8*64);
            gld16(bG + k0 + (size_t)j*8*D_, bL + j*8*64);
        }
        __syncthreads();
#pragma unroll
        for (int half = 0; half < 2; half++) {
            int pc = (half*4 + qd) ^ lm7;
            s8v afr[4], bfr[4];
#pragma unroll
            for (int x = 0; x < 4; x++) {
                afr[x] = *(const s8v*)(As + ((wm*64 + x*16 + lm)*8 + pc)*8);
                bfr[x] = *(const s8v*)(Bs + ((wn*64 + x*16 + lm)*8 + pc)*8);
            }
#pragma unroll
            for (int mt = 0; mt < 4; mt++)
#pragma unroll
                for (int nt = 0; nt < 4; nt++)
                    acc[mt][nt] = MFMA16(afr[mt], bfr[nt], acc[mt][nt]);
        }
    }
}

// ---------------------------------------------------------------------------
// K1: QKV projection + RoPE, all in registers. grid = (32, 24).
// Q is written PRE-SCALED by SCALE2 (folds softmax scale into the GEMM).
// ---------------------------------------------------------------------------
__global__ __launch_bounds__(256, 2) void qkv_mfma_kernel(
    const unsigned short* __restrict__ Xb,
    const unsigned short* __restrict__ Wqb, const unsigned short* __restrict__ Wkb,
    const unsigned short* __restrict__ Wvb, const float2* __restrict__ cst,
    unsigned short* __restrict__ Q, unsigned short* __restrict__ K,
    unsigned short* __restrict__ Vt)
{
    __shared__ __align__(16) short As[8192], Bs[8192];
    int bx = blockIdx.x, by = blockIdx.y;
    int proj = by >> 3, f8 = by & 7;
    int l = threadIdx.x & 63, w = threadIdx.x >> 6;
    int wm = w >> 1, wn = w & 1, lm = l & 15, qd = l >> 4;

    f4v acc[4][4];
    if (proj < 2) {
        const unsigned short* Wm = proj ? Wkb : Wqb;
        mfma_128x128(Wm, Xb, f8*128, bx*128, As, Bs, acc);

        int b  = (bx*128) >> 11;
        int sb = ((bx*128) & 2047) + wn*64;
        int bh = b*H_ + f8*2 + wm;
        unsigned short* dst = proj ? K : Q;
        float post = proj ? 1.0f : SCALE2;
#pragma unroll
        for (int mt = 0; mt < 4; mt++) {
            float sgn = (mt < 2) ? -1.f : 1.f;
#pragma unroll
            for (int nt = 0; nt < 4; nt++) {
                int s = sb + nt*16 + lm;
                unsigned short ov[4];
#pragma unroll
                for (int r = 0; r < 4; r++) {
                    int d = mt*16 + qd*4 + r;
                    float2 cs = cst[(d & 31)*S_ + s];
                    float v = acc[mt][nt][r];
                    float p = acc[mt^2][nt][r];
                    ov[r] = f2bf((v*cs.x + sgn*p*cs.y) * post);
                }
                ushort4 ou; ou.x=ov[0]; ou.y=ov[1]; ou.z=ov[2]; ou.w=ov[3];
                *(ushort4*)&dst[((size_t)bh*S_ + s)*HD_ + mt*16 + qd*4] = ou;
            }
        }
    } else {
        mfma_128x128(Xb, Wvb, bx*128, f8*128, As, Bs, acc);

        int b  = (bx*128) >> 11;
        int sb = ((bx*128) & 2047) + wm*64;
        int bh = b*H_ + f8*2 + wn;
#pragma unroll
        for (int mt = 0; mt < 4; mt++)
#pragma unroll
            for (int nt = 0; nt < 4; nt++) {
                int dim = nt*16 + lm;
                int s   = sb + mt*16 + qd*4;
                ushort4 ou;
                ou.x = f2bf(acc[mt][nt][0]);
                ou.y = f2bf(acc[mt][nt][1]);
                ou.z = f2bf(acc[mt][nt][2]);
                ou.w = f2bf(acc[mt][nt][3]);
                *(ushort4*)&Vt[((size_t)bh*HD_ + dim)*S_ + s] = ou;
            }
    }
}

// ---------------------------------------------------------------------------
// K2: flash attention, in-block KV-split x2 (additive partials, fixed-max
// softmax), register-prefetch dbuf staging, 1 barrier/iter, mask as MFMA
// C-initializer, li by MFMA. Block = 512 thr = 8 waves: wave w -> KV half
// w>>2, query group w&3 (32 queries). grid = (S/128, B*H).
// LDS: K dbuf 32K + V dbuf 32K + msk 8K = 72KB -> 2 blocks/CU, 16 waves/CU.
// ---------------------------------------------------------------------------
__global__ __launch_bounds__(512, 4) void flash_mfma_kernel(
    const unsigned short* __restrict__ Q, const unsigned short* __restrict__ K,
    const unsigned short* __restrict__ Vt, const int* __restrict__ mask,
    unsigned short* __restrict__ AO)
{
    __shared__ __align__(16) short Ksh[2][2][4096];   // [kv-half][buf][8fb*512]
    __shared__ __align__(16) short Vsh[2][2][4096];
    __shared__ __align__(16) float msk[S_];

    int bh = blockIdx.y;
    int b = bh >> 4, h = bh & 15;
    int tid = threadIdx.x;
    int l = tid & 63, w = tid >> 6;
    int hk = w >> 2;            // KV half (0: keys 0..1023, 1: 1024..2047)
    int wq = w & 3;             // query group
    int lq = l & 31, hf = l >> 5;
    int q0 = blockIdx.x * 128 + wq * 32;

    {   // mask -> LDS as additive bias (-16 live / -3e38 masked)
        int i0 = tid * 4;
        const int* mp = mask + b * S_ + i0;
#pragma unroll
        for (int jj = 0; jj < 4; jj++)
            msk[i0 + jj] = mp[jj] ? -MXF2 : -3.0e38f;
    }

    const unsigned short* Qr = Q + ((size_t)bh * S_ + q0 + lq) * HD_ + hf * 8;
    s8v qf[4];
#pragma unroll
    for (int dc = 0; dc < 4; dc++) qf[dc] = *(const s8v*)(Qr + dc * 16);

    f16x zz = {0.f};
    f16x oacc[2]; oacc[0] = zz; oacc[1] = zz;
    f16x lacc = zz;
    s8v ones;
#pragma unroll
    for (int j = 0; j < 8; j++) ones[j] = (short)0x3F80;   // bf16 1.0

    const int KH = S_ / 2;      // keys per half
    const unsigned short* Kb = K  + (size_t)bh * S_ * HD_ + (size_t)hk * KH * HD_;
    const unsigned short* Vb = Vt + (size_t)bh * HD_ * S_ + hk * KH;

    int fb0 = 2*wq, fb1 = 2*wq + 1;
    const unsigned short* kS0 = Kb + (size_t)((fb0>>2)*32 + lq) * HD_ + (fb0&3)*16 + hf*8;
    const unsigned short* kS1 = Kb + (size_t)((fb1>>2)*32 + lq) * HD_ + (fb1&3)*16 + hf*8;
    const unsigned short* vS0 = Vb + (size_t)((fb0>>2)*32 + lq) * S_  + (fb0&3)*16 + hf*8;
    const unsigned short* vS1 = Vb + (size_t)((fb1>>2)*32 + lq) * S_  + (fb1&3)*16 + hf*8;

    s8v kr0 = *(const s8v*)(kS0);
    s8v kr1 = *(const s8v*)(kS1);
    s8v vr0 = *(const s8v*)(vS0);
    s8v vr1 = *(const s8v*)(vS1);

    int mbase0 = hk * KH;

#pragma unroll 1
    for (int t = 0; t < KH / 64; t++) {      // 16 iterations
        int buf = t & 1;
        *(s8v*)(&Ksh[hk][buf][fb0*512 + l*8]) = kr0;
        *(s8v*)(&Ksh[hk][buf][fb1*512 + l*8]) = kr1;
        *(s8v*)(&Vsh[hk][buf][fb0*512 + l*8]) = vr0;
        *(s8v*)(&Vsh[hk][buf][fb1*512 + l*8]) = vr1;
        __syncthreads();
        if (t < KH/64 - 1) {                 // prefetch next tile into regs
            int koff = (t + 1) * 64;
            kr0 = *(const s8v*)(kS0 + (size_t)koff * HD_);
            kr1 = *(const s8v*)(kS1 + (size_t)koff * HD_);
            vr0 = *(const s8v*)(vS0 + koff);
            vr1 = *(const s8v*)(vS1 + koff);
        }

        // ---- Sc^T = K.Q^T with mask as C-init ----
        int mb = mbase0 + t*64;
        f16x sa0, sa1;
#pragma unroll
        for (int g = 0; g < 4; g++) {
            f4v m0 = *(const f4v*)&msk[mb + g*8 + hf*4];
            f4v m1 = *(const f4v*)&msk[mb + 32 + g*8 + hf*4];
#pragma unroll
            for (int i = 0; i < 4; i++) { sa0[g*4+i] = m0[i]; sa1[g*4+i] = m1[i]; }
        }
#pragma unroll
        for (int dc = 0; dc < 4; dc++) {
            s8v kf0 = *(const s8v*)(&Ksh[hk][buf][(0*4+dc)*512 + l*8]);
            sa0 = MFMA32(kf0, qf[dc], sa0);
        }
#pragma unroll
        for (int dc = 0; dc < 4; dc++) {
            s8v kf1 = *(const s8v*)(&Ksh[hk][buf][(1*4+dc)*512 + l*8]);
            sa1 = MFMA32(kf1, qf[dc], sa1);
        }

        // ---- p = exp2(sa), chain-free (Q pre-scaled, mask pre-added) ----
        float p[32];
#pragma unroll
        for (int r = 0; r < 16; r++) p[r]      = exp2f(sa0[r]);
#pragma unroll
        for (int r = 0; r < 16; r++) p[16 + r] = exp2f(sa1[r]);

        int pk[16];
#pragma unroll
        for (int m = 0; m < 16; m++)
            pk[m] = __builtin_amdgcn_perm(__float_as_uint(p[2*m+1]),
                                          __float_as_uint(p[2*m]), 0x07060302);

        // ---- P^T B-frags + PV + li-by-MFMA ----
#pragma unroll
        for (int kcc = 0; kcc < 4; kcc++) {
            int a = 4*kcc;
            int x01 = hf ? pk[a]   : pk[a+2];
            int x23 = hf ? pk[a+1] : pk[a+3];
            int y01 = __shfl_xor(x01, 32);
            int y23 = __shfl_xor(x23, 32);
            i4v fr;
            fr.x = hf ? y01 : pk[a];
            fr.y = hf ? y23 : pk[a+1];
            fr.z = hf ? pk[a+2] : y01;
            fr.w = hf ? pk[a+3] : y23;
            s8v pf = __builtin_bit_cast(s8v, fr);
#pragma unroll
            for (int dt = 0; dt < 2; dt++) {
                s8v vf = *(const s8v*)(&Vsh[hk][buf][(dt*4+kcc)*512 + l*8]);
                oacc[dt] = MFMA32(vf, pf, oacc[dt]);
            }
            lacc = MFMA32(ones, pf, lacc);
        }
    }

    // ---- combine the two KV halves (purely additive) ----
    __syncthreads();                         // all reads of Ksh/msk retired
    float* ob = (float*)&Ksh[0][0][0];       // 8192 floats (exactly 32KB)
    float* lb = msk;                         // 256 floats reused
    int cidx = wq*64 + l;
    if (hk == 1) {
#pragma unroll
        for (int dt = 0; dt < 2; dt++)
#pragma unroll
            for (int r = 0; r < 16; r++)
                ob[(dt*16 + r)*256 + cidx] = oacc[dt][r];
        lb[cidx] = lacc[0];
    }
    __syncthreads();
    if (hk == 0) {
        float invl = 1.0f / (lacc[0] + lb[cidx]);
        int qtok = q0 + lq;
        unsigned short* Or = AO + ((size_t)(b * S_ + qtok)) * D_ + h * HD_;
#pragma unroll
        for (int dt = 0; dt < 2; dt++)
#pragma unroll
            for (int g = 0; g < 4; g++) {
                int d0 = dt*32 + g*8 + hf*4;
                ushort4 o;
                o.x = f2bf((oacc[dt][g*4+0] + ob[(dt*16+g*4+0)*256 + cidx]) * invl);
                o.y = f2bf((oacc[dt][g*4+1] + ob[(dt*16+g*4+1)*256 + cidx]) * invl);
                o.z = f2bf((oacc[dt][g*4+2] + ob[(dt*16+g*4+2)*256 + cidx]) * invl);
                o.w = f2bf((oacc[dt][g*4+3] + ob[(dt*16+g*4+3)*256 + cidx]) * invl);
                *(ushort4*)&Or[d0] = o;
            }
    }
}

// ---------------------------------------------------------------------------
// K3: output projection as C[e][token] = Wo . AO^T; float4 register stores.
// ---------------------------------------------------------------------------
__global__ __launch_bounds__(256, 2) void outproj_mfma_kernel(
    const unsigned short* __restrict__ AO, const unsigned short* __restrict__ Wob,
    float* __restrict__ out)
{
    __shared__ __align__(16) short As[8192], Bs[8192];
    int bx = blockIdx.x, by = blockIdx.y;
    int l = threadIdx.x & 63, w = threadIdx.x >> 6;
    int wm = w >> 1, wn = w & 1, lm = l & 15, qd = l >> 4;

    f4v acc[4][4];
    mfma_128x128(Wob, AO, by*128, bx*128, As, Bs, acc);

#pragma unroll
    for (int mt = 0; mt < 4; mt++)
#pragma unroll
        for (int nt = 0; nt < 4; nt++) {
            int tok = bx*128 + wn*64 + nt*16 + lm;
            int e   = by*128 + wm*64 + mt*16 + qd*4;
            *(f4v*)&out[(size_t)tok*D_ + e] = acc[mt][nt];
        }
}

// ---------------------------------------------------------------------------
// Workspace (u16 units): Xb 4M | W*b 1M x4 | Qb 4M | Kb 4M | Vtb 4M | AOb 4M
// | cst (float2) 64K  ~= 48.5 MB
// ---------------------------------------------------------------------------
extern "C" void kernel_launch(void* const* d_in, const int* in_sizes, int n_in,
                              void* d_out, int out_size, void* d_ws, size_t ws_size,
                              hipStream_t stream)
{
    const float* X    = (const float*)d_in[0];
    const int*   mask = (const int*)  d_in[1];
    const float* Wq   = (const float*)d_in[2];
    const float* Wk   = (const float*)d_in[3];
    const float* Wv   = (const float*)d_in[4];
    const float* Wo   = (const float*)d_in[5];
    float* out = (float*)d_out;

    unsigned short* ws = (unsigned short*)d_ws;
    unsigned short* Xb  = ws;
    unsigned short* Wqb = Xb  + (size_t)M_ * D_;
    unsigned short* Wkb = Wqb + (size_t)D_ * D_;
    unsigned short* Wvb = Wkb + (size_t)D_ * D_;
    unsigned short* Wob = Wvb + (size_t)D_ * D_;
    unsigned short* Qb  = Wob + (size_t)D_ * D_;
    unsigned short* Kb  = Qb  + (size_t)M_ * D_;
    unsigned short* Vtb = Kb  + (size_t)M_ * D_;
    unsigned short* AOb = Vtb + (size_t)M_ * D_;
    float2* cst = (float2*)(AOb + (size_t)M_ * D_);

    cvt_bf16_kernel<<<dim3(4096, 6), 256, 0, stream>>>(
        X, Wq, Wk, Wv, Wo, Xb, Wqb, Wkb, Wvb, Wob, cst);
    qkv_mfma_kernel<<<dim3(32, 24), 256, 0, stream>>>(
        Xb, Wqb, Wkb, Wvb, cst, Qb, Kb, Vtb);
    flash_mfma_kernel<<<dim3(S_ / 128, B_ * H_), 512, 0, stream>>>(
        Qb, Kb, Vtb, mask, AOb);
    outproj_mfma_kernel<<<dim3(32, 8), 256, 0, stream>>>(AOb, Wob, out);
}

// Round 11
// 201.121 us; speedup vs baseline: 1.2221x; 1.2221x over previous
//
#include <hip/hip_runtime.h>
#include <math.h>

#define B_  2
#define S_  2048
#define D_  1024
#define H_  16
#define HD_ 64
#define M_  (B_*S_)

typedef __attribute__((ext_vector_type(8)))  short s8v;   // 8 bf16 (4 VGPRs)
typedef __attribute__((ext_vector_type(4)))  int   i4v;
typedef __attribute__((ext_vector_type(4)))  float f4v;
typedef __attribute__((ext_vector_type(16))) float f16x;  // 32x32 C/D
#define MFMA16(a,b,c) __builtin_amdgcn_mfma_f32_16x16x32_bf16(a,b,c,0,0,0)
#define MFMA32(a,b,c) __builtin_amdgcn_mfma_f32_32x32x16_bf16(a,b,c,0,0,0)

typedef __attribute__((address_space(1))) const unsigned int uint_ga;
typedef __attribute__((address_space(3))) unsigned int       uint_ls;

__device__ __forceinline__ unsigned short f2bf(float x) {   // RNE
    unsigned u = __float_as_uint(x);
    u += 0x7FFF + ((u >> 16) & 1);
    return (unsigned short)(u >> 16);
}
// async global->LDS, 16B per lane; LDS dest = wave-uniform base + lane*16
__device__ __forceinline__ void gld16(const unsigned short* g, short* l) {
    __builtin_amdgcn_global_load_lds((uint_ga*)g, (uint_ls*)l, 16, 0, 0);
}

#define SCALE2 0.1803368801111204f   /* 0.125 * log2(e) */
#define MXF2   16.0f

// ---------------------------------------------------------------------------
// fp32 -> bf16 for X and weights + RoPE table (fused). grid = (4096, 6)
// y==5: cos/sin table, packed float2, layout [j=0..31][s]
// ---------------------------------------------------------------------------
__global__ __launch_bounds__(256) void cvt_bf16_kernel(
    const float* __restrict__ X,  const float* __restrict__ Wq,
    const float* __restrict__ Wk, const float* __restrict__ Wv,
    const float* __restrict__ Wo,
    unsigned short* __restrict__ Xb,  unsigned short* __restrict__ Wqb,
    unsigned short* __restrict__ Wkb, unsigned short* __restrict__ Wvb,
    unsigned short* __restrict__ Wob, float2* __restrict__ cst)
{
    int y = blockIdx.y;
    if (y == 5) {
        int i = blockIdx.x * 256 + threadIdx.x;
        if (i < S_ * 32) {
            int j = i >> 11, s = i & 2047;
            double inv = pow(10000.0, -(double)j / 32.0);
            double ang = (double)s * inv;
            cst[i] = make_float2((float)cos(ang), (float)sin(ang));
        }
        return;
    }
    const float* src = (y==0)?X:(y==1)?Wq:(y==2)?Wk:(y==3)?Wv:Wo;
    unsigned short* dst = (y==0)?Xb:(y==1)?Wqb:(y==2)?Wkb:(y==3)?Wvb:Wob;
    int n = (y==0) ? (M_*D_) : (D_*D_);
    int i = (blockIdx.x*256 + threadIdx.x)*4;
    if (i >= n) return;
    float4 v = *(const float4*)&src[i];
    ushort4 o;
    o.x = f2bf(v.x); o.y = f2bf(v.y); o.z = f2bf(v.z); o.w = f2bf(v.w);
    *(ushort4*)&dst[i] = o;
}

// ---------------------------------------------------------------------------
// m97-style GEMM core: 128x128 tile of C = A . B^T (both row-major, K=D_
// contiguous). 256 thr = 4 waves; wave (wm,wn) owns a 64x64 quadrant,
// 4x4 MFMA16 accs. Staging: global_load_lds dwordx4, XOR chunk swizzle.
// ---------------------------------------------------------------------------
__device__ __forceinline__ void mfma_128x128(
    const unsigned short* __restrict__ Amat, const unsigned short* __restrict__ Bmat,
    int m0, int n0, short* As, short* Bs, f4v acc[4][4])
{
    int tid = threadIdx.x;
    int l = tid & 63, w = tid >> 6;
    int wm = w >> 1, wn = w & 1;
    int lm = l & 15, qd = l >> 4;
    int lm7 = lm & 7;

    f4v z = {0.f, 0.f, 0.f, 0.f};
#pragma unroll
    for (int mt = 0; mt < 4; mt++)
#pragma unroll
        for (int nt = 0; nt < 4; nt++) acc[mt][nt] = z;

    int rl = l >> 3;              // 0..7 row-in-group
    int kc = (l & 7) ^ rl;        // swizzled logical chunk to fetch
    const unsigned short* aG = Amat + (size_t)(m0 + w*32 + rl) * D_ + kc*8;
    const unsigned short* bG = Bmat + (size_t)(n0 + w*32 + rl) * D_ + kc*8;
    short* aL = As + (w*32)*64;
    short* bL = Bs + (w*32)*64;

#pragma unroll 1
    for (int k0 = 0; k0 < D_; k0 += 64) {
        __syncthreads();
#pragma unroll
        for (int j = 0; j < 4; j++) {
            gld16(aG + k0 + (size_t)j*8*D_, aL + j*8*64);
            gld16(bG + k0 + (size_t)j*8*D_, bL + j*8*64);
        }
        __syncthreads();
#pragma unroll
        for (int half = 0; half < 2; half++) {
            int pc = (half*4 + qd) ^ lm7;
            s8v afr[4], bfr[4];
#pragma unroll
            for (int x = 0; x < 4; x++) {
                afr[x] = *(const s8v*)(As + ((wm*64 + x*16 + lm)*8 + pc)*8);
                bfr[x] = *(const s8v*)(Bs + ((wn*64 + x*16 + lm)*8 + pc)*8);
            }
#pragma unroll
            for (int mt = 0; mt < 4; mt++)
#pragma unroll
                for (int nt = 0; nt < 4; nt++)
                    acc[mt][nt] = MFMA16(afr[mt], bfr[nt], acc[mt][nt]);
        }
    }
}

// ---------------------------------------------------------------------------
// K1: QKV projection + RoPE, all in registers. grid = (32, 24).
// Q is written PRE-SCALED by SCALE2 (folds softmax scale into the GEMM).
// ---------------------------------------------------------------------------
__global__ __launch_bounds__(256, 2) void qkv_mfma_kernel(
    const unsigned short* __restrict__ Xb,
    const unsigned short* __restrict__ Wqb, const unsigned short* __restrict__ Wkb,
    const unsigned short* __restrict__ Wvb, const float2* __restrict__ cst,
    unsigned short* __restrict__ Q, unsigned short* __restrict__ K,
    unsigned short* __restrict__ Vt)
{
    __shared__ __align__(16) short As[8192], Bs[8192];
    int bx = blockIdx.x, by = blockIdx.y;
    int proj = by >> 3, f8 = by & 7;
    int l = threadIdx.x & 63, w = threadIdx.x >> 6;
    int wm = w >> 1, wn = w & 1, lm = l & 15, qd = l >> 4;

    f4v acc[4][4];
    if (proj < 2) {
        const unsigned short* Wm = proj ? Wkb : Wqb;
        mfma_128x128(Wm, Xb, f8*128, bx*128, As, Bs, acc);

        int b  = (bx*128) >> 11;
        int sb = ((bx*128) & 2047) + wn*64;
        int bh = b*H_ + f8*2 + wm;
        unsigned short* dst = proj ? K : Q;
        float post = proj ? 1.0f : SCALE2;
#pragma unroll
        for (int mt = 0; mt < 4; mt++) {
            float sgn = (mt < 2) ? -1.f : 1.f;
#pragma unroll
            for (int nt = 0; nt < 4; nt++) {
                int s = sb + nt*16 + lm;
                unsigned short ov[4];
#pragma unroll
                for (int r = 0; r < 4; r++) {
                    int d = mt*16 + qd*4 + r;
                    float2 cs = cst[(d & 31)*S_ + s];
                    float v = acc[mt][nt][r];
                    float p = acc[mt^2][nt][r];
                    ov[r] = f2bf((v*cs.x + sgn*p*cs.y) * post);
                }
                ushort4 ou; ou.x=ov[0]; ou.y=ov[1]; ou.z=ov[2]; ou.w=ov[3];
                *(ushort4*)&dst[((size_t)bh*S_ + s)*HD_ + mt*16 + qd*4] = ou;
            }
        }
    } else {
        mfma_128x128(Xb, Wvb, bx*128, f8*128, As, Bs, acc);

        int b  = (bx*128) >> 11;
        int sb = ((bx*128) & 2047) + wm*64;
        int bh = b*H_ + f8*2 + wn;
#pragma unroll
        for (int mt = 0; mt < 4; mt++)
#pragma unroll
            for (int nt = 0; nt < 4; nt++) {
                int dim = nt*16 + lm;
                int s   = sb + mt*16 + qd*4;
                ushort4 ou;
                ou.x = f2bf(acc[mt][nt][0]);
                ou.y = f2bf(acc[mt][nt][1]);
                ou.z = f2bf(acc[mt][nt][2]);
                ou.w = f2bf(acc[mt][nt][3]);
                *(ushort4*)&Vt[((size_t)bh*HD_ + dim)*S_ + s] = ou;
            }
    }
}

// ---------------------------------------------------------------------------
// K2: flash attention. 256 thr = 4 waves, wave w -> queries q0+w*32..+31,
// full 2048-key sweep, 32 iterations of 64 keys.
// Register-prefetch LDS double-buffer, ONE barrier per iteration
// (write buf -> barrier -> prefetch regs -> compute; reads of a buffer at
// iter t-2 are fenced from its rewrite at t by the barrier at t-1).
// Fixed-max softmax (Q pre-scaled; mask folded into MFMA C-init);
// li accumulated by MFMA with ones-A; P packed via v_perm truncation.
// LDS: K dbuf 16K + V dbuf 16K + msk 8K = 40 KB.
// ---------------------------------------------------------------------------
__global__ __launch_bounds__(256, 2) void flash_mfma_kernel(
    const unsigned short* __restrict__ Q, const unsigned short* __restrict__ K,
    const unsigned short* __restrict__ Vt, const int* __restrict__ mask,
    unsigned short* __restrict__ AO)
{
    __shared__ __align__(16) short Ksh[2][4096];
    __shared__ __align__(16) short Vsh[2][4096];
    __shared__ __align__(16) float msk[S_];

    int bh = blockIdx.y;
    int b = bh >> 4, h = bh & 15;
    int tid = threadIdx.x;
    int l = tid & 63, w = tid >> 6;
    int lq = l & 31, hf = l >> 5;
    int q0 = blockIdx.x * 128 + w * 32;

    {   // mask -> LDS as additive bias (-16 live / -3e38 masked)
        int i0 = tid * 8;
        const int* mp = mask + b * S_ + i0;
#pragma unroll
        for (int jj = 0; jj < 8; jj++)
            msk[i0 + jj] = mp[jj] ? -MXF2 : -3.0e38f;
    }

    const unsigned short* Qr = Q + ((size_t)bh * S_ + q0 + lq) * HD_ + hf * 8;
    s8v qf[4];
#pragma unroll
    for (int dc = 0; dc < 4; dc++) qf[dc] = *(const s8v*)(Qr + dc * 16);

    f16x zz = {0.f};
    f16x oacc[2]; oacc[0] = zz; oacc[1] = zz;
    f16x lacc = zz;
    s8v ones;
#pragma unroll
    for (int j = 0; j < 8; j++) ones[j] = (short)0x3F80;   // bf16 1.0

    const unsigned short* Kb = K  + (size_t)bh * S_ * HD_;
    const unsigned short* Vb = Vt + (size_t)bh * HD_ * S_;

    int fb0 = 2*w, fb1 = 2*w + 1;
    const unsigned short* kS0 = Kb + (size_t)((fb0>>2)*32 + lq) * HD_ + (fb0&3)*16 + hf*8;
    const unsigned short* kS1 = Kb + (size_t)((fb1>>2)*32 + lq) * HD_ + (fb1&3)*16 + hf*8;
    const unsigned short* vS0 = Vb + (size_t)((fb0>>2)*32 + lq) * S_  + (fb0&3)*16 + hf*8;
    const unsigned short* vS1 = Vb + (size_t)((fb1>>2)*32 + lq) * S_  + (fb1&3)*16 + hf*8;

    s8v kr0 = *(const s8v*)(kS0);
    s8v kr1 = *(const s8v*)(kS1);
    s8v vr0 = *(const s8v*)(vS0);
    s8v vr1 = *(const s8v*)(vS1);

#pragma unroll 1
    for (int t = 0; t < S_ / 64; t++) {      // 32 iterations
        int buf = t & 1;
        *(s8v*)(&Ksh[buf][fb0*512 + l*8]) = kr0;
        *(s8v*)(&Ksh[buf][fb1*512 + l*8]) = kr1;
        *(s8v*)(&Vsh[buf][fb0*512 + l*8]) = vr0;
        *(s8v*)(&Vsh[buf][fb1*512 + l*8]) = vr1;
        __syncthreads();
        if (t < S_/64 - 1) {                 // prefetch next tile into regs
            int koff = (t + 1) * 64;
            kr0 = *(const s8v*)(kS0 + (size_t)koff * HD_);
            kr1 = *(const s8v*)(kS1 + (size_t)koff * HD_);
            vr0 = *(const s8v*)(vS0 + koff);
            vr1 = *(const s8v*)(vS1 + koff);
        }

        // ---- Sc^T = K.Q^T with mask as C-init ----
        int mb = t * 64;
        f16x sa0, sa1;
#pragma unroll
        for (int g = 0; g < 4; g++) {
            f4v m0 = *(const f4v*)&msk[mb + g*8 + hf*4];
            f4v m1 = *(const f4v*)&msk[mb + 32 + g*8 + hf*4];
#pragma unroll
            for (int i = 0; i < 4; i++) { sa0[g*4+i] = m0[i]; sa1[g*4+i] = m1[i]; }
        }
#pragma unroll
        for (int dc = 0; dc < 4; dc++) {
            s8v kf0 = *(const s8v*)(&Ksh[buf][(0*4+dc)*512 + l*8]);
            sa0 = MFMA32(kf0, qf[dc], sa0);
        }
#pragma unroll
        for (int dc = 0; dc < 4; dc++) {
            s8v kf1 = *(const s8v*)(&Ksh[buf][(1*4+dc)*512 + l*8]);
            sa1 = MFMA32(kf1, qf[dc], sa1);
        }

        // ---- p = exp2(sa), chain-free ----
        float p[32];
#pragma unroll
        for (int r = 0; r < 16; r++) p[r]      = exp2f(sa0[r]);
#pragma unroll
        for (int r = 0; r < 16; r++) p[16 + r] = exp2f(sa1[r]);

        int pk[16];
#pragma unroll
        for (int m = 0; m < 16; m++)
            pk[m] = __builtin_amdgcn_perm(__float_as_uint(p[2*m+1]),
                                          __float_as_uint(p[2*m]), 0x07060302);

        // ---- P^T B-frags + PV + li-by-MFMA ----
#pragma unroll
        for (int kcc = 0; kcc < 4; kcc++) {
            int a = 4*kcc;
            int x01 = hf ? pk[a]   : pk[a+2];
            int x23 = hf ? pk[a+1] : pk[a+3];
            int y01 = __shfl_xor(x01, 32);
            int y23 = __shfl_xor(x23, 32);
            i4v fr;
            fr.x = hf ? y01 : pk[a];
            fr.y = hf ? y23 : pk[a+1];
            fr.z = hf ? pk[a+2] : y01;
            fr.w = hf ? pk[a+3] : y23;
            s8v pf = __builtin_bit_cast(s8v, fr);
#pragma unroll
            for (int dt = 0; dt < 2; dt++) {
                s8v vf = *(const s8v*)(&Vsh[buf][(dt*4+kcc)*512 + l*8]);
                oacc[dt] = MFMA32(vf, pf, oacc[dt]);
            }
            lacc = MFMA32(ones, pf, lacc);
        }
    }

    float invl = 1.0f / lacc[0];        // complete row-sum (B-frag spans keys)
    int qtok = q0 + lq;
    unsigned short* Or = AO + ((size_t)(b * S_ + qtok)) * D_ + h * HD_;
#pragma unroll
    for (int dt = 0; dt < 2; dt++)
#pragma unroll
        for (int g = 0; g < 4; g++) {
            int d0 = dt*32 + g*8 + hf*4;
            ushort4 o;
            o.x = f2bf(oacc[dt][g*4 + 0] * invl);
            o.y = f2bf(oacc[dt][g*4 + 1] * invl);
            o.z = f2bf(oacc[dt][g*4 + 2] * invl);
            o.w = f2bf(oacc[dt][g*4 + 3] * invl);
            *(ushort4*)&Or[d0] = o;
        }
}

// ---------------------------------------------------------------------------
// K3: output projection as C[e][token] = Wo . AO^T; float4 register stores.
// ---------------------------------------------------------------------------
__global__ __launch_bounds__(256, 2) void outproj_mfma_kernel(
    const unsigned short* __restrict__ AO, const unsigned short* __restrict__ Wob,
    float* __restrict__ out)
{
    __shared__ __align__(16) short As[8192], Bs[8192];
    int bx = blockIdx.x, by = blockIdx.y;
    int l = threadIdx.x & 63, w = threadIdx.x >> 6;
    int wm = w >> 1, wn = w & 1, lm = l & 15, qd = l >> 4;

    f4v acc[4][4];
    mfma_128x128(Wob, AO, by*128, bx*128, As, Bs, acc);

#pragma unroll
    for (int mt = 0; mt < 4; mt++)
#pragma unroll
        for (int nt = 0; nt < 4; nt++) {
            int tok = bx*128 + wn*64 + nt*16 + lm;
            int e   = by*128 + wm*64 + mt*16 + qd*4;
            *(f4v*)&out[(size_t)tok*D_ + e] = acc[mt][nt];
        }
}

// ---------------------------------------------------------------------------
// Workspace (u16 units): Xb 4M | W*b 1M x4 | Qb 4M | Kb 4M | Vtb 4M | AOb 4M
// | cst (float2) 64K  ~= 48.5 MB
// ---------------------------------------------------------------------------
extern "C" void kernel_launch(void* const* d_in, const int* in_sizes, int n_in,
                              void* d_out, int out_size, void* d_ws, size_t ws_size,
                              hipStream_t stream)
{
    const float* X    = (const float*)d_in[0];
    const int*   mask = (const int*)  d_in[1];
    const float* Wq   = (const float*)d_in[2];
    const float* Wk   = (const float*)d_in[3];
    const float* Wv   = (const float*)d_in[4];
    const float* Wo   = (const float*)d_in[5];
    float* out = (float*)d_out;

    unsigned short* ws = (unsigned short*)d_ws;
    unsigned short* Xb  = ws;
    unsigned short* Wqb = Xb  + (size_t)M_ * D_;
    unsigned short* Wkb = Wqb + (size_t)D_ * D_;
    unsigned short* Wvb = Wkb + (size_t)D_ * D_;
    unsigned short* Wob = Wvb + (size_t)D_ * D_;
    unsigned short* Qb  = Wob + (size_t)D_ * D_;
    unsigned short* Kb  = Qb  + (size_t)M_ * D_;
    unsigned short* Vtb = Kb  + (size_t)M_ * D_;
    unsigned short* AOb = Vtb + (size_t)M_ * D_;
    float2* cst = (float2*)(AOb + (size_t)M_ * D_);

    cvt_bf16_kernel<<<dim3(4096, 6), 256, 0, stream>>>(
        X, Wq, Wk, Wv, Wo, Xb, Wqb, Wkb, Wvb, Wob, cst);
    qkv_mfma_kernel<<<dim3(32, 24), 256, 0, stream>>>(
        Xb, Wqb, Wkb, Wvb, cst, Qb, Kb, Vtb);
    flash_mfma_kernel<<<dim3(S_ / 128, B_ * H_), 256, 0, stream>>>(
        Qb, Kb, Vtb, mask, AOb);
    outproj_mfma_kernel<<<dim3(32, 8), 256, 0, stream>>>(AOb, Wob, out);
}